// Round 6
// baseline (144.634 us; speedup 1.0000x reference)
//
#include <hip/hip_runtime.h>

#define NROWS 100000
#define IN_DIM 512

typedef __attribute__((ext_vector_type(8))) short short8;
typedef __attribute__((ext_vector_type(4))) float f32x4;
typedef unsigned int u32;
typedef const __attribute__((address_space(1))) u32* gptr_t;
typedef __attribute__((address_space(3))) u32* lptr_t;

__device__ inline unsigned short f2bf(float f) {
    union { float f; unsigned u; } v; v.f = f;
    unsigned u = v.u;
    return (unsigned short)((u + 0x7FFFu + ((u >> 16) & 1u)) >> 16);
}

// Prepack: build B-fragments (bf16) in exact MFMA lane order + fused que bias.
// B = [80 cols x 512 k]: cols 0..63 = Wv, 64..71 = Wq@Wk, 72..79 = 0.
// Bp layout: [t(5)][ks(16)][lane(64)][e(8)] bf16; col = t*16+(lane&15),
// k = ks*32 + (lane>>4)*8 + e.
__global__ void qg_prepack(const float* __restrict__ Wk, const float* __restrict__ bk,
                           const float* __restrict__ Wq, const float* __restrict__ bq,
                           const float* __restrict__ Wv,
                           unsigned short* __restrict__ Bp, float* __restrict__ qb) {
    int id = blockIdx.x * 256 + threadIdx.x;  // 0..5119
    if (id < 8) {
        float s = bq[id];
        #pragma unroll 4
        for (int j = 0; j < 100; ++j) s += Wq[id * 100 + j] * bk[j];
        qb[id] = s;
    }
    if (id >= 5120) return;
    int lane = id & 63;
    int ks = (id >> 6) & 15;
    int t = id >> 10;
    int c = t * 16 + (lane & 15);
    int kk = ks * 32 + (lane >> 4) * 8;
    short8 pk;
    #pragma unroll
    for (int e = 0; e < 8; ++e) {
        int k2 = kk + e;
        float w;
        if (c < 64) {
            w = Wv[c * IN_DIM + k2];
        } else if (c < 72) {
            float s = 0.f;
            #pragma unroll 4
            for (int j = 0; j < 100; ++j) s += Wq[(c - 64) * 100 + j] * Wk[j * IN_DIM + k2];
            w = s;
        } else {
            w = 0.f;
        }
        pk[e] = (short)f2bf(w);
    }
    ((short8*)Bp)[id] = pk;
}

// Main: 64 threads = ONE wave per block, 16 rows/block, grid 6250 (exact).
// ALL loads issued upfront: 80 B-loads -> VGPRs, 32 global_load_lds A-stages
// (16 steps x 2KB, XOR-swizzled source / linear LDS dest). Counted vmcnt
// ladder consumes steps; no barriers anywhere. NT stores for out.
__global__ __launch_bounds__(64, 1) void qg_main(const float* __restrict__ x,
                                                 const float* __restrict__ bv,
                                                 const unsigned short* __restrict__ Bp,
                                                 const float* __restrict__ qb,
                                                 float* __restrict__ out) {
    __shared__ float xs[16 * 512];      // 32 KB: [step][row(16) x chunkf4(8)] linear
    __shared__ float vlds[16][68];
    __shared__ float wlds[16][8];
    const int lane = threadIdx.x;       // 0..63
    const int g = lane >> 4;            // k sub-block
    const int cl = lane & 15;           // row-within-tile / col-within-tile
    const int rowbase = blockIdx.x * 16;

    const short8* bp8 = (const short8*)Bp + lane;

    // ---- Issue ALL B loads (80 x 1KB wave-wide, L2-resident) ----
    short8 B[16][5];
    #pragma unroll
    for (int s = 0; s < 16; ++s)
        #pragma unroll
        for (int t = 0; t < 5; ++t)
            B[s][t] = bp8[(t * 16 + s) * 64];

    // ---- Issue ALL A stages (32 x global_load_lds dwordx4) ----
    // dest: linear, base + lane*16B. source: pre-swizzled chunk (ch ^ (row&7)).
    {
        int o4a = lane, o4b = 64 + lane;
        int rowa = o4a >> 3, cha = o4a & 7;
        int rowb = o4b >> 3, chb = o4b & 7;
        const float* srca = x + (size_t)(rowbase + rowa) * IN_DIM + (cha ^ (rowa & 7)) * 4;
        const float* srcb = x + (size_t)(rowbase + rowb) * IN_DIM + (chb ^ (rowb & 7)) * 4;
        #pragma unroll
        for (int s = 0; s < 16; ++s) {
            __builtin_amdgcn_global_load_lds((gptr_t)(const void*)(srca + s * 32),
                (lptr_t)(void*)&xs[s * 512 + o4a * 4], 16, 0, 0);
            __builtin_amdgcn_global_load_lds((gptr_t)(const void*)(srcb + s * 32),
                (lptr_t)(void*)&xs[s * 512 + o4b * 4], 16, 0, 0);
        }
    }

    f32x4 acc[5];
    #pragma unroll
    for (int t = 0; t < 5; ++t) acc[t] = (f32x4){0.f, 0.f, 0.f, 0.f};

    // Consume step S after waiting vmcnt(NW). Correct for any VMEM issue order:
    // worst-case FIFO pos of stage(S) = 82+2S of 112 -> outstanding <= 30-2S.
    #define QSTEP(S, NW) do {                                                  \
        asm volatile("s_waitcnt vmcnt(" #NW ")" ::: "memory");                 \
        const float4* xs4_ = (const float4*)&xs[(S) * 512];                    \
        float4 f0_ = xs4_[cl * 8 + ((g * 2) ^ (cl & 7))];                      \
        float4 f1_ = xs4_[cl * 8 + ((g * 2 + 1) ^ (cl & 7))];                  \
        short8 af_;                                                            \
        af_[0] = (short)f2bf(f0_.x); af_[1] = (short)f2bf(f0_.y);              \
        af_[2] = (short)f2bf(f0_.z); af_[3] = (short)f2bf(f0_.w);              \
        af_[4] = (short)f2bf(f1_.x); af_[5] = (short)f2bf(f1_.y);              \
        af_[6] = (short)f2bf(f1_.z); af_[7] = (short)f2bf(f1_.w);              \
        acc[0] = __builtin_amdgcn_mfma_f32_16x16x32_bf16(af_, B[S][0], acc[0], 0, 0, 0); \
        acc[1] = __builtin_amdgcn_mfma_f32_16x16x32_bf16(af_, B[S][1], acc[1], 0, 0, 0); \
        acc[2] = __builtin_amdgcn_mfma_f32_16x16x32_bf16(af_, B[S][2], acc[2], 0, 0, 0); \
        acc[3] = __builtin_amdgcn_mfma_f32_16x16x32_bf16(af_, B[S][3], acc[3], 0, 0, 0); \
        acc[4] = __builtin_amdgcn_mfma_f32_16x16x32_bf16(af_, B[S][4], acc[4], 0, 0, 0); \
    } while (0)

    QSTEP(0, 30);  QSTEP(1, 28);  QSTEP(2, 26);  QSTEP(3, 24);
    QSTEP(4, 22);  QSTEP(5, 20);  QSTEP(6, 18);  QSTEP(7, 16);
    QSTEP(8, 14);  QSTEP(9, 12);  QSTEP(10, 10); QSTEP(11, 8);
    QSTEP(12, 6);  QSTEP(13, 4);  QSTEP(14, 2);  QSTEP(15, 0);
    #undef QSTEP

    // ---- Epilogue (single wave, lockstep; lgkmcnt ordering only) ----
    // C layout: col = lane&15, row = (lane>>4)*4 + reg  (verified m89).
    #pragma unroll
    for (int t = 0; t < 4; ++t) {
        float b = bv[t * 16 + cl];
        #pragma unroll
        for (int r = 0; r < 4; ++r)
            vlds[g * 4 + r][t * 16 + cl] = acc[t][r] + b;
    }
    if (cl < 8) {
        float b = qb[cl];
        #pragma unroll
        for (int r = 0; r < 4; ++r)
            wlds[g * 4 + r][cl] = acc[4][r] + b;
    }
    asm volatile("s_waitcnt lgkmcnt(0)" ::: "memory");

    // Softmax over the 8 que values: lanes 0..15 each own one row.
    if (lane < 16) {
        float q[8];
        float m = -1e30f;
        #pragma unroll
        for (int k = 0; k < 8; ++k) { q[k] = wlds[lane][k]; m = fmaxf(m, q[k]); }
        float ssum = 0.f;
        #pragma unroll
        for (int k = 0; k < 8; ++k) { q[k] = __expf(q[k] - m); ssum += q[k]; }
        float inv = 1.f / ssum;
        #pragma unroll
        for (int k = 0; k < 8; ++k) wlds[lane][k] = q[k] * inv;
    }
    asm volatile("s_waitcnt lgkmcnt(0)" ::: "memory");

    // Coalesced NONTEMPORAL output: out[row][k][v] = w[k] * val[v].
    // Per iteration: one full 512-float row half -> contiguous 1 KB store.
    f32x4* outp = (f32x4*)out + (size_t)rowbase * 128;
    #pragma unroll
    for (int it = 0; it < 32; ++it) {
        int idx = it * 64 + lane;
        int row = idx >> 7;             // 0..15
        int j = idx & 127;              // float4 index within 512-float out row
        float wgt = wlds[row][j >> 4];
        float4 vv = *(const float4*)&vlds[row][(j & 15) * 4];
        f32x4 o;
        o[0] = wgt * vv.x; o[1] = wgt * vv.y; o[2] = wgt * vv.z; o[3] = wgt * vv.w;
        __builtin_nontemporal_store(o, &outp[(size_t)row * 128 + j]);
    }
}

extern "C" void kernel_launch(void* const* d_in, const int* in_sizes, int n_in,
                              void* d_out, int out_size, void* d_ws, size_t ws_size,
                              hipStream_t stream) {
    const float* x  = (const float*)d_in[0];
    const float* Wk = (const float*)d_in[1];
    const float* bk = (const float*)d_in[2];
    const float* Wq = (const float*)d_in[3];
    const float* bq = (const float*)d_in[4];
    const float* Wv = (const float*)d_in[5];
    const float* bv = (const float*)d_in[6];
    float* out = (float*)d_out;

    unsigned short* Bp = (unsigned short*)d_ws;          // 5*16*64*8 bf16 = 81920 B
    float* qb = (float*)((char*)d_ws + 81920);           // 8 floats

    qg_prepack<<<20, 256, 0, stream>>>(Wk, bk, Wq, bq, Wv, Bp, qb);
    qg_main<<<6250, 64, 0, stream>>>(x, bv, Bp, qb, out);
}

// Round 7
// 126.529 us; speedup vs baseline: 1.1431x; 1.1431x over previous
//
#include <hip/hip_runtime.h>

#define NROWS 100000
#define IN_DIM 512

typedef __attribute__((ext_vector_type(8))) short short8;
typedef __attribute__((ext_vector_type(4))) float f32x4;

__device__ inline unsigned short f2bf(float f) {
    union { float f; unsigned u; } v; v.f = f;
    unsigned u = v.u;
    return (unsigned short)((u + 0x7FFFu + ((u >> 16) & 1u)) >> 16);
}

// Prepack: B-fragments (bf16) in exact MFMA lane order + fused que bias.
// B = [80 cols x 512 k]: cols 0..63 = Wv, 64..71 = Wq@Wk, 72..79 = 0.
__global__ void qg_prepack(const float* __restrict__ Wk, const float* __restrict__ bk,
                           const float* __restrict__ Wq, const float* __restrict__ bq,
                           const float* __restrict__ Wv,
                           unsigned short* __restrict__ Bp, float* __restrict__ qb) {
    int id = blockIdx.x * 256 + threadIdx.x;  // 0..5119
    if (id < 8) {
        float s = bq[id];
        #pragma unroll 4
        for (int j = 0; j < 100; ++j) s += Wq[id * 100 + j] * bk[j];
        qb[id] = s;
    }
    if (id >= 5120) return;
    int lane = id & 63;
    int ks = (id >> 6) & 15;
    int t = id >> 10;
    int c = t * 16 + (lane & 15);
    int kk = ks * 32 + (lane >> 4) * 8;
    short8 pk;
    #pragma unroll
    for (int e = 0; e < 8; ++e) {
        int k2 = kk + e;
        float w;
        if (c < 64) {
            w = Wv[c * IN_DIM + k2];
        } else if (c < 72) {
            float s = 0.f;
            #pragma unroll 4
            for (int j = 0; j < 100; ++j) s += Wq[(c - 64) * 100 + j] * Wk[j * IN_DIM + k2];
            w = s;
        } else {
            w = 0.f;
        }
        pk[e] = (short)f2bf(w);
    }
    ((short8*)Bp)[id] = pk;
}

// k1: GEMM -> compact. 128 threads = 2 independent waves, 16 rows/wave, no
// barriers. Writes ONLY w[8]+val[64] per row into that row's output tail:
// out[r][440..448) = softmax weights, out[r][448..512) = val+bias. Cached
// stores (want L3 residency for k2).
__global__ __launch_bounds__(128, 4) void qg_gemm(const float* __restrict__ x,
                                                  const float* __restrict__ bv,
                                                  const unsigned short* __restrict__ Bp,
                                                  const float* __restrict__ qb,
                                                  float* __restrict__ out) {
    __shared__ float vlds[2][16][68];
    __shared__ float wlds[2][16][8];
    const int tid = threadIdx.x;
    const int w = tid >> 6;
    const int lane = tid & 63;
    const int g = lane >> 4;
    const int cl = lane & 15;
    const int rowbase = blockIdx.x * 32 + w * 16;   // 3125*32 = 100000 exact

    const float* ap = x + (size_t)(rowbase + cl) * IN_DIM + g * 8;
    const short8* bp8 = (const short8*)Bp + lane;

    f32x4 acc[5];
    #pragma unroll
    for (int t = 0; t < 5; ++t) acc[t] = (f32x4){0.f, 0.f, 0.f, 0.f};

    float4 A[3][2];
    short8 B[2][5];
    #pragma unroll
    for (int p = 0; p < 3; ++p) {
        A[p][0] = *(const float4*)(ap + p * 32);
        A[p][1] = *(const float4*)(ap + p * 32 + 4);
    }
    #pragma unroll
    for (int p = 0; p < 2; ++p)
        #pragma unroll
        for (int t = 0; t < 5; ++t)
            B[p][t] = bp8[(t * 16 + p) * 64];

    #pragma unroll
    for (int s = 0; s < 16; ++s) {
        const int ai = s % 3, bi = s % 2;
        float4 f0 = A[ai][0];
        float4 f1 = A[ai][1];
        short8 af;
        af[0] = (short)f2bf(f0.x); af[1] = (short)f2bf(f0.y);
        af[2] = (short)f2bf(f0.z); af[3] = (short)f2bf(f0.w);
        af[4] = (short)f2bf(f1.x); af[5] = (short)f2bf(f1.y);
        af[6] = (short)f2bf(f1.z); af[7] = (short)f2bf(f1.w);
        if (s + 3 < 16) {
            A[ai][0] = *(const float4*)(ap + (s + 3) * 32);
            A[ai][1] = *(const float4*)(ap + (s + 3) * 32 + 4);
        }
        #pragma unroll
        for (int t = 0; t < 5; ++t)
            acc[t] = __builtin_amdgcn_mfma_f32_16x16x32_bf16(af, B[bi][t], acc[t], 0, 0, 0);
        if (s + 2 < 16) {
            #pragma unroll
            for (int t = 0; t < 5; ++t)
                B[bi][t] = bp8[(t * 16 + s + 2) * 64];
        }
    }

    // Per-wave epilogue. C layout: col = lane&15, row = (lane>>4)*4 + reg (m89).
    #pragma unroll
    for (int t = 0; t < 4; ++t) {
        float b = bv[t * 16 + cl];
        #pragma unroll
        for (int r = 0; r < 4; ++r)
            vlds[w][g * 4 + r][t * 16 + cl] = acc[t][r] + b;
    }
    if (cl < 8) {
        float b = qb[cl];
        #pragma unroll
        for (int r = 0; r < 4; ++r)
            wlds[w][g * 4 + r][cl] = acc[4][r] + b;
    }
    asm volatile("s_waitcnt lgkmcnt(0)" ::: "memory");

    if (lane < 16) {
        float q[8];
        float m = -1e30f;
        #pragma unroll
        for (int k = 0; k < 8; ++k) { q[k] = wlds[w][lane][k]; m = fmaxf(m, q[k]); }
        float ssum = 0.f;
        #pragma unroll
        for (int k = 0; k < 8; ++k) { q[k] = __expf(q[k] - m); ssum += q[k]; }
        float inv = 1.f / ssum;
        #pragma unroll
        for (int k = 0; k < 8; ++k) wlds[w][lane][k] = q[k] * inv;
    }
    asm volatile("s_waitcnt lgkmcnt(0)" ::: "memory");

    // Compact store to row tails.
    // val: 16 rows x 16 float4 -> 4 instrs.
    #pragma unroll
    for (int it = 0; it < 4; ++it) {
        int idx = it * 64 + lane;
        int row = idx >> 4;
        int v4 = idx & 15;
        float4 vv = *(const float4*)&vlds[w][row][v4 * 4];
        *(float4*)(out + (size_t)(rowbase + row) * 512 + 448 + v4 * 4) = vv;
    }
    // w: 16 rows x 8 -> 2 instrs.
    #pragma unroll
    for (int it = 0; it < 2; ++it) {
        int idx = it * 64 + lane;
        int row = idx >> 3;
        int kk = idx & 7;
        out[(size_t)(rowbase + row) * 512 + 440 + kk] = wlds[w][row][kk];
    }
}

// k2: expand. 256 threads = 4 independent waves, 16 rows/wave. Read each
// row's compact tail (L3-hot), stage in per-wave LDS, NT-store the full row.
__global__ __launch_bounds__(256) void qg_expand(float* __restrict__ out) {
    __shared__ float vlds[4][16][68];
    __shared__ float wlds[4][16][8];
    const int tid = threadIdx.x;
    const int w = tid >> 6;
    const int lane = tid & 63;
    const int rowbase = blockIdx.x * 64 + w * 16;

    // Load compact (clamped rows for OOB waves; stores are guarded).
    #pragma unroll
    for (int it = 0; it < 4; ++it) {
        int idx = it * 64 + lane;
        int row = idx >> 4;
        int v4 = idx & 15;
        int gr = min(rowbase + row, NROWS - 1);
        float4 vv = *(const float4*)(out + (size_t)gr * 512 + 448 + v4 * 4);
        *(float4*)&vlds[w][row][v4 * 4] = vv;
    }
    #pragma unroll
    for (int it = 0; it < 2; ++it) {
        int idx = it * 64 + lane;
        int row = idx >> 3;
        int kk = idx & 7;
        int gr = min(rowbase + row, NROWS - 1);
        wlds[w][row][kk] = out[(size_t)gr * 512 + 440 + kk];
    }
    asm volatile("s_waitcnt vmcnt(0) lgkmcnt(0)" ::: "memory");

    // NT store full rows: out[row][k][v] = w[k] * val[v]; 1 KB/instr.
    f32x4* outp = (f32x4*)out + (size_t)rowbase * 128;
    #pragma unroll
    for (int it = 0; it < 32; ++it) {
        int idx = it * 64 + lane;
        int row = idx >> 7;
        int j = idx & 127;
        if (rowbase + row < NROWS) {
            float wgt = wlds[w][row][j >> 4];
            float4 vv = *(const float4*)&vlds[w][row][(j & 15) * 4];
            f32x4 o;
            o[0] = wgt * vv.x; o[1] = wgt * vv.y; o[2] = wgt * vv.z; o[3] = wgt * vv.w;
            __builtin_nontemporal_store(o, &outp[(size_t)row * 128 + j]);
        }
    }
}

extern "C" void kernel_launch(void* const* d_in, const int* in_sizes, int n_in,
                              void* d_out, int out_size, void* d_ws, size_t ws_size,
                              hipStream_t stream) {
    const float* x  = (const float*)d_in[0];
    const float* Wk = (const float*)d_in[1];
    const float* bk = (const float*)d_in[2];
    const float* Wq = (const float*)d_in[3];
    const float* bq = (const float*)d_in[4];
    const float* Wv = (const float*)d_in[5];
    const float* bv = (const float*)d_in[6];
    float* out = (float*)d_out;

    unsigned short* Bp = (unsigned short*)d_ws;          // 81920 B
    float* qb = (float*)((char*)d_ws + 81920);           // 8 floats

    qg_prepack<<<20, 256, 0, stream>>>(Wk, bk, Wq, bq, Wv, Bp, qb);
    qg_gemm<<<3125, 128, 0, stream>>>(x, bv, Bp, qb, out);
    qg_expand<<<1563, 256, 0, stream>>>(out);
}

// Round 8
// 104.352 us; speedup vs baseline: 1.3860x; 1.2125x over previous
//
#include <hip/hip_runtime.h>

#define NROWS 100000
#define IN_DIM 512

typedef __attribute__((ext_vector_type(8))) short short8;
typedef __attribute__((ext_vector_type(4))) float f32x4;

__device__ inline unsigned short f2bf(float f) {
    union { float f; unsigned u; } v; v.f = f;
    unsigned u = v.u;
    return (unsigned short)((u + 0x7FFFu + ((u >> 16) & 1u)) >> 16);
}

// Prepack: B-fragments (bf16) in exact MFMA lane order + fused que bias.
// B = [80 cols x 512 k]: cols 0..63 = Wv, 64..71 = Wq@Wk, 72..79 = 0.
// Bp layout: [t(5)][ks(16)][lane(64)][e(8)] bf16; col = t*16+(lane&15),
// k = ks*32 + (lane>>4)*8 + e.
__global__ void qg_prepack(const float* __restrict__ Wk, const float* __restrict__ bk,
                           const float* __restrict__ Wq, const float* __restrict__ bq,
                           const float* __restrict__ Wv,
                           unsigned short* __restrict__ Bp, float* __restrict__ qb) {
    int id = blockIdx.x * 256 + threadIdx.x;  // 0..5119
    if (id < 8) {
        float s = bq[id];
        #pragma unroll 4
        for (int j = 0; j < 100; ++j) s += Wq[id * 100 + j] * bk[j];
        qb[id] = s;
    }
    if (id >= 5120) return;
    int lane = id & 63;
    int ks = (id >> 6) & 15;
    int t = id >> 10;
    int c = t * 16 + (lane & 15);
    int kk = ks * 32 + (lane >> 4) * 8;
    short8 pk;
    #pragma unroll
    for (int e = 0; e < 8; ++e) {
        int k2 = kk + e;
        float w;
        if (c < 64) {
            w = Wv[c * IN_DIM + k2];
        } else if (c < 72) {
            float s = 0.f;
            #pragma unroll 4
            for (int j = 0; j < 100; ++j) s += Wq[(c - 64) * 100 + j] * Wk[j * IN_DIM + k2];
            w = s;
        } else {
            w = 0.f;
        }
        pk[e] = (short)f2bf(w);
    }
    ((short8*)Bp)[id] = pk;
}

// Main: 128 threads = 2 independent waves, 32 rows/wave (2 M-tiles), no
// barriers. Prefetches pinned early via sched_barrier(0); NT stores for out.
__global__ __launch_bounds__(128, 2) void qg_main(const float* __restrict__ x,
                                                  const float* __restrict__ bv,
                                                  const unsigned short* __restrict__ Bp,
                                                  const float* __restrict__ qb,
                                                  float* __restrict__ out) {
    __shared__ float vlds[2][32][68];
    __shared__ float wlds[2][32][8];
    const int tid = threadIdx.x;
    const int w = tid >> 6;
    const int lane = tid & 63;
    const int g = lane >> 4;       // k sub-block (k = g*8+e within a 32-K step)
    const int cl = lane & 15;      // A row within tile / B col within tile
    const int rowbase = (blockIdx.x * 2 + w) * 32;   // 1563*64 covers 100000

    const float* ap0 = x + (size_t)min(rowbase + cl,      NROWS - 1) * IN_DIM + g * 8;
    const float* ap1 = x + (size_t)min(rowbase + 16 + cl, NROWS - 1) * IN_DIM + g * 8;
    const short8* bp8 = (const short8*)Bp + lane;

    f32x4 acc[2][5];
    #pragma unroll
    for (int m = 0; m < 2; ++m)
        #pragma unroll
        for (int t = 0; t < 5; ++t) acc[m][t] = (f32x4){0.f, 0.f, 0.f, 0.f};

    float4 A[2][2][2];   // [slot][tile][half] — 2-step-deep A prefetch
    short8 B[3][5];      // 3-slot B buffer — 2-step-deep prefetch

    // Prologue: steps 0,1 in flight.
    #pragma unroll
    for (int p = 0; p < 2; ++p) {
        A[p][0][0] = *(const float4*)(ap0 + p * 32);
        A[p][0][1] = *(const float4*)(ap0 + p * 32 + 4);
        A[p][1][0] = *(const float4*)(ap1 + p * 32);
        A[p][1][1] = *(const float4*)(ap1 + p * 32 + 4);
        #pragma unroll
        for (int t = 0; t < 5; ++t) B[p][t] = bp8[(t * 16 + p) * 64];
    }

    #pragma unroll
    for (int s = 0; s < 16; ++s) {
        const int ai = s & 1, bi = s % 3;
        // Convert current A (reads old slot value before the overwrite below).
        short8 af[2];
        #pragma unroll
        for (int m = 0; m < 2; ++m) {
            float4 f0 = A[ai][m][0];
            float4 f1 = A[ai][m][1];
            af[m][0] = (short)f2bf(f0.x); af[m][1] = (short)f2bf(f0.y);
            af[m][2] = (short)f2bf(f0.z); af[m][3] = (short)f2bf(f0.w);
            af[m][4] = (short)f2bf(f1.x); af[m][5] = (short)f2bf(f1.y);
            af[m][6] = (short)f2bf(f1.z); af[m][7] = (short)f2bf(f1.w);
        }
        // Issue prefetches for step s+2, then pin them with sched_barrier so
        // the scheduler cannot sink them past this point.
        if (s + 2 < 16) {
            A[ai][0][0] = *(const float4*)(ap0 + (s + 2) * 32);
            A[ai][0][1] = *(const float4*)(ap0 + (s + 2) * 32 + 4);
            A[ai][1][0] = *(const float4*)(ap1 + (s + 2) * 32);
            A[ai][1][1] = *(const float4*)(ap1 + (s + 2) * 32 + 4);
            #pragma unroll
            for (int t = 0; t < 5; ++t)
                B[(s + 2) % 3][t] = bp8[(t * 16 + s + 2) * 64];
        }
        __builtin_amdgcn_sched_barrier(0);
        #pragma unroll
        for (int t = 0; t < 5; ++t)
            acc[0][t] = __builtin_amdgcn_mfma_f32_16x16x32_bf16(af[0], B[bi][t], acc[0][t], 0, 0, 0);
        #pragma unroll
        for (int t = 0; t < 5; ++t)
            acc[1][t] = __builtin_amdgcn_mfma_f32_16x16x32_bf16(af[1], B[bi][t], acc[1][t], 0, 0, 0);
    }

    // ---- Per-wave epilogue (intra-wave lockstep; lgkmcnt ordering only) ----
    // C layout: col = lane&15, row = (lane>>4)*4 + reg  (verified m89).
    #pragma unroll
    for (int t = 0; t < 4; ++t) {
        float b = bv[t * 16 + cl];
        #pragma unroll
        for (int m = 0; m < 2; ++m)
            #pragma unroll
            for (int r = 0; r < 4; ++r)
                vlds[w][m * 16 + g * 4 + r][t * 16 + cl] = acc[m][t][r] + b;
    }
    if (cl < 8) {
        float b = qb[cl];
        #pragma unroll
        for (int m = 0; m < 2; ++m)
            #pragma unroll
            for (int r = 0; r < 4; ++r)
                wlds[w][m * 16 + g * 4 + r][cl] = acc[m][4][r] + b;
    }
    asm volatile("s_waitcnt lgkmcnt(0)" ::: "memory");

    // Softmax over the 8 que values: lanes 0..31 each own one row.
    if (lane < 32) {
        float q[8];
        float m = -1e30f;
        #pragma unroll
        for (int k = 0; k < 8; ++k) { q[k] = wlds[w][lane][k]; m = fmaxf(m, q[k]); }
        float ssum = 0.f;
        #pragma unroll
        for (int k = 0; k < 8; ++k) { q[k] = __expf(q[k] - m); ssum += q[k]; }
        float inv = 1.f / ssum;
        #pragma unroll
        for (int k = 0; k < 8; ++k) wlds[w][lane][k] = q[k] * inv;
    }
    asm volatile("s_waitcnt lgkmcnt(0)" ::: "memory");

    // Coalesced NONTEMPORAL output: out[row][k][v] = w[k] * val[v];
    // per-instr = contiguous 1 KB, streams past L2/L3.
    f32x4* outp = (f32x4*)out + (size_t)rowbase * 128;
    #pragma unroll
    for (int it = 0; it < 64; ++it) {
        int idx = it * 64 + lane;
        int row = idx >> 7;             // 0..31
        int j = idx & 127;              // float4 index within 512-float out row
        if (rowbase + row < NROWS) {
            float wgt = wlds[w][row][j >> 4];
            float4 vv = *(const float4*)&vlds[w][row][(j & 15) * 4];
            f32x4 o;
            o[0] = wgt * vv.x; o[1] = wgt * vv.y; o[2] = wgt * vv.z; o[3] = wgt * vv.w;
            __builtin_nontemporal_store(o, &outp[(size_t)row * 128 + j]);
        }
    }
}

extern "C" void kernel_launch(void* const* d_in, const int* in_sizes, int n_in,
                              void* d_out, int out_size, void* d_ws, size_t ws_size,
                              hipStream_t stream) {
    const float* x  = (const float*)d_in[0];
    const float* Wk = (const float*)d_in[1];
    const float* bk = (const float*)d_in[2];
    const float* Wq = (const float*)d_in[3];
    const float* bq = (const float*)d_in[4];
    const float* Wv = (const float*)d_in[5];
    const float* bv = (const float*)d_in[6];
    float* out = (float*)d_out;

    unsigned short* Bp = (unsigned short*)d_ws;          // 81920 B
    float* qb = (float*)((char*)d_ws + 81920);           // 8 floats

    qg_prepack<<<20, 256, 0, stream>>>(Wk, bk, Wq, bq, Wv, Bp, qb);
    qg_main<<<1563, 128, 0, stream>>>(x, bv, Bp, qb, out);
}

// Round 10
// 101.994 us; speedup vs baseline: 1.4181x; 1.0231x over previous
//
#include <hip/hip_runtime.h>

#define NROWS 100000
#define IN_DIM 512

typedef __attribute__((ext_vector_type(8))) short short8;
typedef __attribute__((ext_vector_type(4))) float f32x4;

__device__ inline unsigned short f2bf(float f) {
    union { float f; unsigned u; } v; v.f = f;
    unsigned u = v.u;
    return (unsigned short)((u + 0x7FFFu + ((u >> 16) & 1u)) >> 16);
}

// Prepack: B-fragments (bf16) in exact MFMA lane order + fused que bias.
// B = [80 cols x 512 k]: cols 0..63 = Wv, 64..71 = Wq@Wk, 72..79 = 0.
// Bp layout: [t(5)][ks(16)][lane(64)][e(8)] bf16; col = t*16+(lane&15),
// k = ks*32 + (lane>>4)*8 + e.
__global__ void qg_prepack(const float* __restrict__ Wk, const float* __restrict__ bk,
                           const float* __restrict__ Wq, const float* __restrict__ bq,
                           const float* __restrict__ Wv,
                           unsigned short* __restrict__ Bp, float* __restrict__ qb) {
    int id = blockIdx.x * 256 + threadIdx.x;  // 0..5119
    if (id < 8) {
        float s = bq[id];
        #pragma unroll 4
        for (int j = 0; j < 100; ++j) s += Wq[id * 100 + j] * bk[j];
        qb[id] = s;
    }
    if (id >= 5120) return;
    int lane = id & 63;
    int ks = (id >> 6) & 15;
    int t = id >> 10;
    int c = t * 16 + (lane & 15);
    int kk = ks * 32 + (lane >> 4) * 8;
    short8 pk;
    #pragma unroll
    for (int e = 0; e < 8; ++e) {
        int k2 = kk + e;
        float w;
        if (c < 64) {
            w = Wv[c * IN_DIM + k2];
        } else if (c < 72) {
            float s = 0.f;
            #pragma unroll 4
            for (int j = 0; j < 100; ++j) s += Wq[(c - 64) * 100 + j] * Wk[j * IN_DIM + k2];
            w = s;
        } else {
            w = 0.f;
        }
        pk[e] = (short)f2bf(w);
    }
    ((short8*)Bp)[id] = pk;
}

// Main: 256 threads = 4 independent waves, 16 rows/wave, no barriers.
// ALL main-loop VMEM is inline-asm global_load_dwordx4 with a hand-counted
// vmcnt ladder (batch = 7 loads/step, 3 batches in flight, vmcnt(14)).
// The compiler cannot sink/rematerialize asm loads -> true deep queue.
__global__ __launch_bounds__(256, 2) void qg_main(const float* __restrict__ x,
                                                  const float* __restrict__ bv,
                                                  const unsigned short* __restrict__ Bp,
                                                  const float* __restrict__ qb,
                                                  float* __restrict__ out) {
    __shared__ float vlds[4][16][68];
    __shared__ float wlds[4][16][8];
    const int tid = threadIdx.x;
    const int w = tid >> 6;
    const int lane = tid & 63;
    const int g = lane >> 4;       // k sub-block (k = g*8+e within a 32-K step)
    const int cl = lane & 15;      // A row within tile / B col within tile
    const int rowbase = blockIdx.x * 64 + w * 16;   // 1563*64 = 100032 covers N
    const int arow = min(rowbase + cl, NROWS - 1);

    const unsigned voffA = (unsigned)(arow * 512 + g * 8) * 4u;  // byte off in x
    const unsigned voffB = (unsigned)lane * 16u;                 // byte off in Bp

    // Bias preload — completed (vmcnt(0)) before the asm region so the
    // compiler's waitcnt model never overlaps the hand-counted FIFO.
    float bvr[4];
    #pragma unroll
    for (int t = 0; t < 4; ++t) bvr[t] = bv[t * 16 + cl];
    float qbr = qb[cl & 7];
    asm volatile("s_waitcnt vmcnt(0)" ::: "memory");

    f32x4 A0[4], A1[4];      // A ring: 2 x dwordx4 per step
    short8 Bv[4][5];         // B ring: 5 x dwordx4 per step
    f32x4 acc[5];
    #pragma unroll
    for (int t = 0; t < 5; ++t) acc[t] = (f32x4){0.f, 0.f, 0.f, 0.f};

#define GLD(dst, off, base, IMM)                                               \
    asm volatile("global_load_dwordx4 %0, %1, %2 offset:" IMM                  \
                 : "=&v"(dst) : "v"(off), "s"(base) : "memory")

#define ISSUE(S) do {                                                          \
        unsigned va_ = voffA + (S) * 128u;                                     \
        GLD(A0[(S) & 3], va_, x, "0");                                         \
        GLD(A1[(S) & 3], va_, x, "16");                                        \
        GLD(Bv[(S) & 3][0], voffB + (0 * 16 + (S)) * 1024u, Bp, "0");          \
        GLD(Bv[(S) & 3][1], voffB + (1 * 16 + (S)) * 1024u, Bp, "0");          \
        GLD(Bv[(S) & 3][2], voffB + (2 * 16 + (S)) * 1024u, Bp, "0");          \
        GLD(Bv[(S) & 3][3], voffB + (3 * 16 + (S)) * 1024u, Bp, "0");          \
        GLD(Bv[(S) & 3][4], voffB + (4 * 16 + (S)) * 1024u, Bp, "0");          \
    } while (0)

#define CONSUME(S, NW) do {                                                    \
        asm volatile("s_waitcnt vmcnt(" NW ")" ::: "memory");                  \
        __builtin_amdgcn_sched_barrier(0);                                     \
        f32x4 f0_ = A0[(S) & 3];                                               \
        f32x4 f1_ = A1[(S) & 3];                                               \
        short8 af_;                                                            \
        af_[0] = (short)f2bf(f0_[0]); af_[1] = (short)f2bf(f0_[1]);            \
        af_[2] = (short)f2bf(f0_[2]); af_[3] = (short)f2bf(f0_[3]);            \
        af_[4] = (short)f2bf(f1_[0]); af_[5] = (short)f2bf(f1_[1]);            \
        af_[6] = (short)f2bf(f1_[2]); af_[7] = (short)f2bf(f1_[3]);            \
        acc[0] = __builtin_amdgcn_mfma_f32_16x16x32_bf16(af_, Bv[(S)&3][0], acc[0], 0, 0, 0); \
        acc[1] = __builtin_amdgcn_mfma_f32_16x16x32_bf16(af_, Bv[(S)&3][1], acc[1], 0, 0, 0); \
        acc[2] = __builtin_amdgcn_mfma_f32_16x16x32_bf16(af_, Bv[(S)&3][2], acc[2], 0, 0, 0); \
        acc[3] = __builtin_amdgcn_mfma_f32_16x16x32_bf16(af_, Bv[(S)&3][3], acc[3], 0, 0, 0); \
        acc[4] = __builtin_amdgcn_mfma_f32_16x16x32_bf16(af_, Bv[(S)&3][4], acc[4], 0, 0, 0); \
    } while (0)

    // Prologue: 3 batches (21 loads) in flight.
    ISSUE(0); ISSUE(1); ISSUE(2);
    // Steady state: consume s (after vmcnt(14): batches s+1,s+2 = 14 loads
    // may remain), then issue batch s+3.
    CONSUME(0, "14");  ISSUE(3);
    CONSUME(1, "14");  ISSUE(4);
    CONSUME(2, "14");  ISSUE(5);
    CONSUME(3, "14");  ISSUE(6);
    CONSUME(4, "14");  ISSUE(7);
    CONSUME(5, "14");  ISSUE(8);
    CONSUME(6, "14");  ISSUE(9);
    CONSUME(7, "14");  ISSUE(10);
    CONSUME(8, "14");  ISSUE(11);
    CONSUME(9, "14");  ISSUE(12);
    CONSUME(10, "14"); ISSUE(13);
    CONSUME(11, "14"); ISSUE(14);
    CONSUME(12, "14"); ISSUE(15);
    CONSUME(13, "14");
    CONSUME(14, "7");
    CONSUME(15, "0");
#undef GLD
#undef ISSUE
#undef CONSUME

    // ---- Per-wave epilogue (intra-wave lockstep; lgkmcnt ordering only) ----
    // C layout: col = lane&15, row = (lane>>4)*4 + reg  (verified m89).
    #pragma unroll
    for (int t = 0; t < 4; ++t) {
        #pragma unroll
        for (int r = 0; r < 4; ++r)
            vlds[w][g * 4 + r][t * 16 + cl] = acc[t][r] + bvr[t];
    }
    if (cl < 8) {
        #pragma unroll
        for (int r = 0; r < 4; ++r)
            wlds[w][g * 4 + r][cl] = acc[4][r] + qbr;
    }
    asm volatile("s_waitcnt lgkmcnt(0)" ::: "memory");

    // Softmax over the 8 que values: lanes 0..15 each own one row.
    if (lane < 16) {
        float q[8];
        float m = -1e30f;
        #pragma unroll
        for (int k = 0; k < 8; ++k) { q[k] = wlds[w][lane][k]; m = fmaxf(m, q[k]); }
        float ssum = 0.f;
        #pragma unroll
        for (int k = 0; k < 8; ++k) { q[k] = __expf(q[k] - m); ssum += q[k]; }
        float inv = 1.f / ssum;
        #pragma unroll
        for (int k = 0; k < 8; ++k) wlds[w][lane][k] = q[k] * inv;
    }
    asm volatile("s_waitcnt lgkmcnt(0)" ::: "memory");

    // Coalesced NONTEMPORAL output: out[row][k][v] = w[k] * val[v];
    // per-instr = contiguous 1 KB, streams past L2/L3.
    f32x4* outp = (f32x4*)out + (size_t)rowbase * 128;
    #pragma unroll
    for (int it = 0; it < 32; ++it) {
        int idx = it * 64 + lane;
        int row = idx >> 7;             // 0..15
        int j = idx & 127;              // float4 index within 512-float out row
        if (rowbase + row < NROWS) {
            float wgt = wlds[w][row][j >> 4];
            float4 vv = *(const float4*)&vlds[w][row][(j & 15) * 4];
            f32x4 o;
            o[0] = wgt * vv.x; o[1] = wgt * vv.y; o[2] = wgt * vv.z; o[3] = wgt * vv.w;
            __builtin_nontemporal_store(o, &outp[(size_t)row * 128 + j]);
        }
    }
}

extern "C" void kernel_launch(void* const* d_in, const int* in_sizes, int n_in,
                              void* d_out, int out_size, void* d_ws, size_t ws_size,
                              hipStream_t stream) {
    const float* x  = (const float*)d_in[0];
    const float* Wk = (const float*)d_in[1];
    const float* bk = (const float*)d_in[2];
    const float* Wq = (const float*)d_in[3];
    const float* bq = (const float*)d_in[4];
    const float* Wv = (const float*)d_in[5];
    const float* bv = (const float*)d_in[6];
    float* out = (float*)d_out;

    unsigned short* Bp = (unsigned short*)d_ws;          // 81920 B
    float* qb = (float*)((char*)d_ws + 81920);           // 8 floats

    qg_prepack<<<20, 256, 0, stream>>>(Wk, bk, Wq, bq, Wv, Bp, qb);
    qg_main<<<1563, 256, 0, stream>>>(x, bv, Bp, qb, out);
}